// Round 6
// baseline (458.827 us; speedup 1.0000x reference)
//
#include <hip/hip_runtime.h>
#include <stdint.h>

typedef unsigned short u16;
typedef unsigned int u32;
typedef __bf16 bf16x8 __attribute__((ext_vector_type(8)));
typedef float f32x4 __attribute__((ext_vector_type(4)));

#define SEQ 2048
#define BZ 16
#define DIM 1024

#define WAIT_VM6()   asm volatile("s_waitcnt vmcnt(6)" ::: "memory")
#define WAIT_VM0()   asm volatile("s_waitcnt vmcnt(0)" ::: "memory")
#define WAIT_LGKM0() asm volatile("s_waitcnt lgkmcnt(0)" ::: "memory")
#define MEMFENCE()   asm volatile("" ::: "memory")

__device__ __forceinline__ u16 f2bf(float f) {
    union { float f; u32 u; } a; a.f = f;
    u32 r = a.u + 0x7FFFu + ((a.u >> 16) & 1u);   // RNE
    return (u16)(r >> 16);
}
__device__ __forceinline__ float bf2f(u16 u) {
    union { u32 u; float f; } a; a.u = ((u32)u) << 16;
    return a.f;
}
__device__ __forceinline__ void async16(const u16* g, u16* l) {
    __builtin_amdgcn_global_load_lds(
        (const __attribute__((address_space(1))) void*)g,
        (__attribute__((address_space(3))) void*)l, 16, 0, 0);
}
// first batch index with the same language id
__device__ __forceinline__ int rep_of(const int* __restrict__ lang_ids, int b) {
    int my = lang_ids[b];
    #pragma unroll
    for (int j = 0; j < BZ; j++)
        if (lang_ids[j] == my) return j;
    return b;
}

// ---------------------------------------------------------------------------
// prep: W transposes (64x64 tiles) + bb reduction, one launch.
//   bid < 17*256:  z<16: Wbt[z][f][e] = W[id_z][e][f] (skip dup langs);
//                  z==16: Wt[d][e] = W_base[e][d]
//   bid >= 17*256: bb[b][f] = sum_e b_base[e]*W[id_b][e][f] + bias[id_b][f]
//                  (64 blocks: 16 b x 4 f-chunks; skip dup langs)
// ---------------------------------------------------------------------------
#define TR_BLOCKS (17 * 256)
__global__ void prep_kernel(const float* __restrict__ W,
                            const float* __restrict__ W_base,
                            const float* __restrict__ b_base,
                            const float* __restrict__ bias,
                            const int* __restrict__ lang_ids,
                            const int* __restrict__ dict_len,
                            u16* __restrict__ Wt,
                            u16* __restrict__ Wbt,
                            float* __restrict__ bb)
{
    int bid = blockIdx.x;
    int t = threadIdx.x;
    if (bid >= TR_BLOCKS) {
        // ---- bb part ----
        int bid2 = bid - TR_BLOCKS;               // 0..63
        int b = bid2 >> 2;
        if (rep_of(lang_ids, b) != b) return;     // duplicate language: skip
        int f = (bid2 & 3) * 256 + t;
        int id = dict_len[0] - 1 - lang_ids[b];
        const float* Wp = W + (size_t)id * DIM * DIM + f;
        float s0 = 0.f, s1 = 0.f, s2 = 0.f, s3 = 0.f;
        #pragma unroll 2
        for (int e = 0; e < DIM; e += 4) {
            s0 += b_base[e]     * Wp[(size_t)e * DIM];
            s1 += b_base[e + 1] * Wp[(size_t)(e + 1) * DIM];
            s2 += b_base[e + 2] * Wp[(size_t)(e + 2) * DIM];
            s3 += b_base[e + 3] * Wp[(size_t)(e + 3) * DIM];
        }
        bb[b * DIM + f] = (s0 + s1) + (s2 + s3) + bias[(size_t)id * DIM + f];
        return;
    }
    // ---- transpose part: 64x64 tile ----
    int z  = bid >> 8;                            // 0..16
    int yx = bid & 255;
    int by = yx >> 4, bx = yx & 15;
    const float* S;
    u16* D;
    if (z < BZ) {
        if (rep_of(lang_ids, z) != z) return;     // duplicate language: skip
        int id = dict_len[0] - 1 - lang_ids[z];
        S = W + (size_t)id * DIM * DIM;
        D = Wbt + (size_t)z * DIM * DIM;
    } else {
        S = W_base;
        D = Wt;
    }
    __shared__ float tile[64][65];
    int tx = t & 63, ty = t >> 6;                 // 64 x 4
    int x0 = bx * 64, y0 = by * 64;
    #pragma unroll
    for (int i = 0; i < 16; i++)
        tile[ty + 4 * i][tx] = S[(size_t)(y0 + ty + 4 * i) * DIM + x0 + tx];
    __syncthreads();
    #pragma unroll
    for (int i = 0; i < 16; i++)
        D[(size_t)(x0 + ty + 4 * i) * DIM + y0 + tx] = f2bf(tile[tx][ty + 4 * i]);
}

// ---------------------------------------------------------------------------
// K2: CT[b][f][d] = sum_e Wbt[b][f][e] * Wt[d][e]   (bf16 out)
// block 128(M)x256(N), BK=32, 4 waves, 8x4 frags 16x16x32, counted vmcnt(6).
// grid = 512 blocks, XCD-swizzled, dedup'd.   (round-5 verbatim)
// ---------------------------------------------------------------------------
__global__ __launch_bounds__(256, 2)
void gemm1_kernel(const u16* __restrict__ Wbt,
                  const u16* __restrict__ Wt,
                  const int* __restrict__ lang_ids,
                  u16* __restrict__ CT)
{
    int bid = blockIdx.x;
    int virt = ((bid & 7) << 6) + (bid >> 3);     // bijective, 512 % 8 == 0
    int b    = virt >> 5;                         // 32 blocks per batch
    if (rep_of(lang_ids, b) != b) return;         // duplicate language: skip
    int rem  = virt & 31;
    int m0   = (rem >> 2) << 7;                   // f-tile base (128)
    int n0   = (rem & 3) << 8;                    // d-tile base (256)

    const u16* A = Wbt + (size_t)b * DIM * DIM;   // [f][e]
    const u16* B = Wt;                            // [d][e]
    u16* C = CT + (size_t)b * DIM * DIM;          // [f][d]

    __shared__ u16 As[2 * 128 * 32];
    __shared__ u16 Bs[2 * 256 * 32];

    int tid = threadIdx.x;
    int w = tid >> 6, l = tid & 63;
    int lr = l & 15, quad = l >> 4;

    int srow = l >> 2;                            // row within 16-row group
    int chunk = l & 3;
    const u16* gA[2]; const u16* gB[4];
    int lA[2], lB[4];
    #pragma unroll
    for (int j = 0; j < 2; j++) {
        int row = w * 32 + j * 16 + srow;
        gA[j] = A + (size_t)(m0 + row) * DIM + chunk * 8;
        lA[j] = (w * 32 + j * 16) * 32;           // wave-uniform LDS base
    }
    #pragma unroll
    for (int j = 0; j < 4; j++) {
        int row = w * 64 + j * 16 + srow;
        gB[j] = B + (size_t)(n0 + row) * DIM + chunk * 8;
        lB[j] = (w * 64 + j * 16) * 32;
    }

    f32x4 acc[8][4];
    #pragma unroll
    for (int m = 0; m < 8; m++)
        #pragma unroll
        for (int n = 0; n < 4; n++)
            #pragma unroll
            for (int e = 0; e < 4; e++) acc[m][n][e] = 0.f;

    #pragma unroll
    for (int j = 0; j < 2; j++) { async16(gA[j], As + lA[j]); gA[j] += 32; }
    #pragma unroll
    for (int j = 0; j < 4; j++) { async16(gB[j], Bs + lB[j]); gB[j] += 32; }

    int cur = 0;
    for (int t = 0; t < DIM / 32 - 1; t++) {
        int ao = (cur ^ 1) * 4096, bo = (cur ^ 1) * 8192;
        #pragma unroll
        for (int j = 0; j < 2; j++) { async16(gA[j], As + ao + lA[j]); gA[j] += 32; }
        #pragma unroll
        for (int j = 0; j < 4; j++) { async16(gB[j], Bs + bo + lB[j]); gB[j] += 32; }
        WAIT_VM6();                               // tile-t loads landed
        MEMFENCE(); __builtin_amdgcn_s_barrier(); MEMFENCE();
        __builtin_amdgcn_sched_barrier(0);

        const u16* ra = As + cur * 4096;
        const u16* rb = Bs + cur * 8192;
        bf16x8 af[8], bfv[4];
        #pragma unroll
        for (int m = 0; m < 8; m++)
            af[m] = *(const bf16x8*)&ra[(m * 16 + lr) * 32 + quad * 8];
        #pragma unroll
        for (int n = 0; n < 4; n++)
            bfv[n] = *(const bf16x8*)&rb[(w * 64 + n * 16 + lr) * 32 + quad * 8];
        __builtin_amdgcn_s_setprio(1);
        #pragma unroll
        for (int m = 0; m < 8; m++)
            #pragma unroll
            for (int n = 0; n < 4; n++)
                acc[m][n] = __builtin_amdgcn_mfma_f32_16x16x32_bf16(
                    af[m], bfv[n], acc[m][n], 0, 0, 0);
        __builtin_amdgcn_s_setprio(0);
        __builtin_amdgcn_sched_barrier(0);
        MEMFENCE(); __builtin_amdgcn_s_barrier(); MEMFENCE();
        cur ^= 1;
    }
    {
        WAIT_VM0();
        MEMFENCE(); __builtin_amdgcn_s_barrier(); MEMFENCE();
        __builtin_amdgcn_sched_barrier(0);
        const u16* ra = As + cur * 4096;
        const u16* rb = Bs + cur * 8192;
        bf16x8 af[8], bfv[4];
        #pragma unroll
        for (int m = 0; m < 8; m++)
            af[m] = *(const bf16x8*)&ra[(m * 16 + lr) * 32 + quad * 8];
        #pragma unroll
        for (int n = 0; n < 4; n++)
            bfv[n] = *(const bf16x8*)&rb[(w * 64 + n * 16 + lr) * 32 + quad * 8];
        #pragma unroll
        for (int m = 0; m < 8; m++)
            #pragma unroll
            for (int n = 0; n < 4; n++)
                acc[m][n] = __builtin_amdgcn_mfma_f32_16x16x32_bf16(
                    af[m], bfv[n], acc[m][n], 0, 0, 0);
    }
    #pragma unroll
    for (int m = 0; m < 8; m++) {
        int fr = m0 + m * 16 + quad * 4;
        #pragma unroll
        for (int n = 0; n < 4; n++) {
            int dc = n0 + w * 64 + n * 16 + lr;
            #pragma unroll
            for (int rr = 0; rr < 4; rr++)
                C[(size_t)(fr + rr) * DIM + dc] = f2bf(acc[m][n][rr]);
        }
    }
}

// ---------------------------------------------------------------------------
// K3: out[s][b][f] = sum_d x[s][b][d] * CT[rep_b][f][d] + bb[rep_b][f]
// A read DIRECTLY from f32 x: global->reg->cvt->ds_write (no xb pass).
// B via global_load_lds. One barrier per iter; vmcnt(0) drain post-MFMA.
// grid = 1024 blocks, XCD-swizzled.
// ---------------------------------------------------------------------------
__global__ __launch_bounds__(256, 2)
void gemm2_kernel(const float* __restrict__ x,
                  const u16* __restrict__ CT,
                  const float* __restrict__ bb,
                  const int* __restrict__ lang_ids,
                  float* __restrict__ out)
{
    int bid = blockIdx.x;
    int virt = ((bid & 7) << 7) + (bid >> 3);     // bijective, 1024 % 8 == 0
    int b    = virt >> 6;                         // 64 blocks per batch
    int rb_  = rep_of(lang_ids, b);               // language representative
    int rem  = virt & 63;
    int s0   = (rem >> 2) << 7;                   // s-tile base (128)
    int f0   = (rem & 3) << 8;                    // f-tile base (256)

    const u16* Bm = CT + (size_t)rb_ * DIM * DIM; // [f][d]

    __shared__ u16 As[2 * 128 * 32];
    __shared__ u16 Bs[2 * 256 * 32];

    int tid = threadIdx.x;
    int w = tid >> 6, l = tid & 63;
    int lr = l & 15, quad = l >> 4;

    // A staging: 4 x float4 per thread, rows {arow+32i}, cols acol..acol+3
    int arow = tid >> 3;                          // 0..31
    int acol = (tid & 7) * 4;                     // f32 col within K-tile
    const float* gx[4];
    int lax[4];
    #pragma unroll
    for (int i = 0; i < 4; i++) {
        gx[i] = x + ((size_t)(s0 + arow + 32 * i) * BZ + b) * DIM + acol;
        lax[i] = (arow + 32 * i) * 32 + acol;     // u16 units
    }
    // B staging: 4 async16 per thread
    int srow = l >> 2;
    int chunk = l & 3;
    const u16* gB[4]; int lB[4];
    #pragma unroll
    for (int j = 0; j < 4; j++) {
        int row = w * 64 + j * 16 + srow;
        gB[j] = Bm + (size_t)(f0 + row) * DIM + chunk * 8;
        lB[j] = (w * 64 + j * 16) * 32;
    }

    f32x4 acc[8][4];
    #pragma unroll
    for (int m = 0; m < 8; m++)
        #pragma unroll
        for (int n = 0; n < 4; n++)
            #pragma unroll
            for (int e = 0; e < 4; e++) acc[m][n][e] = 0.f;

    // prologue: stage K-tile 0 into buffer 0
    float4 av[4];
    #pragma unroll
    for (int j = 0; j < 4; j++) { async16(gB[j], Bs + lB[j]); gB[j] += 32; }
    #pragma unroll
    for (int i = 0; i < 4; i++) { av[i] = *(const float4*)gx[i]; gx[i] += 32; }
    #pragma unroll
    for (int i = 0; i < 4; i++) {
        u32 lo = f2bf(av[i].x) | ((u32)f2bf(av[i].y) << 16);
        u32 hi = f2bf(av[i].z) | ((u32)f2bf(av[i].w) << 16);
        *(uint2*)&As[lax[i]] = make_uint2(lo, hi);
    }
    WAIT_VM0();                                   // B-asyncs landed in LDS
    WAIT_LGKM0();                                 // ds_writes visible
    MEMFENCE(); __builtin_amdgcn_s_barrier(); MEMFENCE();
    __builtin_amdgcn_sched_barrier(0);

    int cur = 0;
    for (int t = 0; t < DIM / 32 - 1; t++) {
        int ao = (cur ^ 1) * 4096, bo = (cur ^ 1) * 8192;
        // issue tile t+1: B -> LDS buf^1 (async), A -> regs
        #pragma unroll
        for (int j = 0; j < 4; j++) { async16(gB[j], Bs + bo + lB[j]); gB[j] += 32; }
        #pragma unroll
        for (int i = 0; i < 4; i++) { av[i] = *(const float4*)gx[i]; gx[i] += 32; }
        __builtin_amdgcn_sched_barrier(0);        // pin issues before compute

        // compute tile t from buf[cur]
        const u16* ra = As + cur * 4096;
        const u16* rb = Bs + cur * 8192;
        bf16x8 af[8], bfv[4];
        #pragma unroll
        for (int m = 0; m < 8; m++)
            af[m] = *(const bf16x8*)&ra[(m * 16 + lr) * 32 + quad * 8];
        #pragma unroll
        for (int n = 0; n < 4; n++)
            bfv[n] = *(const bf16x8*)&rb[(w * 64 + n * 16 + lr) * 32 + quad * 8];
        __builtin_amdgcn_s_setprio(1);
        #pragma unroll
        for (int m = 0; m < 8; m++)
            #pragma unroll
            for (int n = 0; n < 4; n++)
                acc[m][n] = __builtin_amdgcn_mfma_f32_16x16x32_bf16(
                    af[m], bfv[n], acc[m][n], 0, 0, 0);
        __builtin_amdgcn_s_setprio(0);
        __builtin_amdgcn_sched_barrier(0);

        // finish tile t+1 staging: drain (hidden under MFMA span), write A
        WAIT_VM0();                               // av ready, B in buf^1
        #pragma unroll
        for (int i = 0; i < 4; i++) {
            u32 lo = f2bf(av[i].x) | ((u32)f2bf(av[i].y) << 16);
            u32 hi = f2bf(av[i].z) | ((u32)f2bf(av[i].w) << 16);
            *(uint2*)&As[ao + lax[i]] = make_uint2(lo, hi);
        }
        WAIT_LGKM0();                             // writes (and reads) retired
        MEMFENCE(); __builtin_amdgcn_s_barrier(); MEMFENCE();
        __builtin_amdgcn_sched_barrier(0);
        cur ^= 1;
    }
    // last tile
    {
        const u16* ra = As + cur * 4096;
        const u16* rb = Bs + cur * 8192;
        bf16x8 af[8], bfv[4];
        #pragma unroll
        for (int m = 0; m < 8; m++)
            af[m] = *(const bf16x8*)&ra[(m * 16 + lr) * 32 + quad * 8];
        #pragma unroll
        for (int n = 0; n < 4; n++)
            bfv[n] = *(const bf16x8*)&rb[(w * 64 + n * 16 + lr) * 32 + quad * 8];
        #pragma unroll
        for (int m = 0; m < 8; m++)
            #pragma unroll
            for (int n = 0; n < 4; n++)
                acc[m][n] = __builtin_amdgcn_mfma_f32_16x16x32_bf16(
                    af[m], bfv[n], acc[m][n], 0, 0, 0);
    }

    #pragma unroll
    for (int n = 0; n < 4; n++) {
        int col = f0 + w * 64 + n * 16 + lr;
        float bv = bb[rb_ * DIM + col];
        #pragma unroll
        for (int m = 0; m < 8; m++) {
            int sr = s0 + m * 16 + quad * 4;
            #pragma unroll
            for (int rr = 0; rr < 4; rr++)
                out[((size_t)(sr + rr) * BZ + b) * DIM + col] = acc[m][n][rr] + bv;
        }
    }
}

extern "C" void kernel_launch(void* const* d_in, const int* in_sizes, int n_in,
                              void* d_out, int out_size, void* d_ws, size_t ws_size,
                              hipStream_t stream)
{
    const float* x        = (const float*)d_in[0];
    const int*   lang_ids = (const int*)d_in[1];
    const float* W_base   = (const float*)d_in[2];
    const float* b_base   = (const float*)d_in[3];
    const float* W        = (const float*)d_in[4];
    const float* bias     = (const float*)d_in[5];
    const int*   dict_len = (const int*)d_in[6];
    float* out = (float*)d_out;

    char* ws = (char*)d_ws;
    u16*  Wt  = (u16*)ws;                                   // 2 MB
    u16*  Wbt = (u16*)(ws + (size_t)(2u << 20));            // 32 MB
    u16*  CT  = (u16*)(ws + (size_t)(34u << 20));           // 32 MB
    float* bb = (float*)(ws + (size_t)(66u << 20));         // 64 KB

    prep_kernel<<<dim3(TR_BLOCKS + 64, 1, 1), 256, 0, stream>>>(
        W, W_base, b_base, bias, lang_ids, dict_len, Wt, Wbt, bb);
    gemm1_kernel<<<dim3(512, 1, 1), 256, 0, stream>>>(Wbt, Wt, lang_ids, CT);
    gemm2_kernel<<<dim3(1024, 1, 1), 256, 0, stream>>>(x, CT, bb, lang_ids, out);
}